// Round 4
// baseline (92.770 us; speedup 1.0000x reference)
//
#include <hip/hip_runtime.h>
#include <stdint.h>

#define N_COLS 256
#define M_ROWS 65536
#define DIM    512
#define TOPK   10
#define NEG_INIT (-3.0e38f)
#define PS     12
#define NBLK   256                 // k1 blocks
#define BLK_M  (M_ROWS / NBLK)     // 256 rows per block
#define NBM    NBLK                // partial lists per n (for k2)

// LDS map (bytes):
//   [0, 131072)        colm8 [ks][kq][n][8B]  (stream phase) | merge lists (tail, 96KB)
//   [131072, 147456)   sim: per-wave 2KB, [nn<64][m<16] bf16
//   [147456, 148480)   rlab (256 int)
#define LDS_SIM  131072
#define LDS_RLAB 147456
#define LDS_TOT  148480

typedef float          f32x4 __attribute__((ext_vector_type(4)));
typedef unsigned short u16x8 __attribute__((ext_vector_type(8)));
typedef unsigned short u16x4 __attribute__((ext_vector_type(4)));

__device__ __forceinline__ unsigned short f2bf(float x) {
    union { float f; unsigned u; } v; v.f = x;
    unsigned r = v.u + 0x7fffu + ((v.u >> 16) & 1u);   // RNE
    return (unsigned short)(r >> 16);
}
__device__ __forceinline__ float bf2f(unsigned short h) {
    union { float f; unsigned u; } v; v.u = ((unsigned)h) << 16; return v.f;
}
__device__ __forceinline__ void gload16(const void* g, void* l) {
    __builtin_amdgcn_global_load_lds(
        (const __attribute__((address_space(1))) void*)g,
        (__attribute__((address_space(3))) void*)l, 16, 0, 0);
}
// pack 8 f32 (pre-scaled) -> 8 fp8 e4m3 in an i64, k-ascending byte order
__device__ __forceinline__ long pack8(float4 a, float4 b) {
    int lo = __builtin_amdgcn_cvt_pk_fp8_f32(a.x, a.y, 0, 0);
    lo = __builtin_amdgcn_cvt_pk_fp8_f32(a.z, a.w, lo, 1);
    int hi = __builtin_amdgcn_cvt_pk_fp8_f32(b.x, b.y, 0, 0);
    hi = __builtin_amdgcn_cvt_pk_fp8_f32(b.z, b.w, hi, 1);
    return (long)(((unsigned long)(unsigned)hi << 32) | (unsigned)lo);
}

// K0: colm f32 -> fp8 (x16 scale) in [ks][kq][n][8] layout (= k1's LDS layout).
__global__ __launch_bounds__(256)
void k0_cvt(const float* __restrict__ colm, unsigned char* __restrict__ colm8) {
    int tid = blockIdx.x * 256 + threadIdx.x;        // 0..16383
    int n = tid >> 6, ks = (tid >> 2) & 15, kq = tid & 3;
    const float* src = colm + n * DIM + ks * 32 + kq * 8;
    float4 a = *(const float4*)src, b = *(const float4*)(src + 4);
    a.x *= 16.f; a.y *= 16.f; a.z *= 16.f; a.w *= 16.f;
    b.x *= 16.f; b.y *= 16.f; b.z *= 16.f; b.w *= 16.f;
    *(long*)(colm8 + ks * 8192 + kq * 2048 + n * 8) = pack8(a, b);
}

// K1: block bm streams rowm rows [bm*256, +256) against LDS-resident colm8
// (full n=256, full k=512). No barriers in the stream loop. Fused per-n top-10
// + positive stats; per-block merge -> part[n][bm].
__global__ __launch_bounds__(512, 2)
void k1_mfma(const unsigned char* __restrict__ colm8g, const int* __restrict__ clab_g,
             const float* __restrict__ rowm, const int* __restrict__ rlab_g,
             float* __restrict__ part) {
    __shared__ __align__(16) char smem[LDS_TOT];
    const int t = threadIdx.x, bm = blockIdx.x;
    const int w = t >> 6, l = t & 63, lq = l >> 4, lc = l & 15;

    // stage colm8 (128KB) via global_load_lds; layout already matches
#pragma unroll
    for (int i = 0; i < 16; ++i)
        gload16(colm8g + i * 8192 + w * 1024 + l * 16,
                (void*)(smem + i * 8192 + w * 1024));
    if (t < 256) ((int*)(smem + LDS_RLAB))[t] = rlab_g[bm * BLK_M + t];

    int clab_i[4];
#pragma unroll
    for (int i = 0; i < 4; ++i) clab_i[i] = clab_g[i * 64 + l];

    float tk[4][TOPK];
#pragma unroll
    for (int i = 0; i < 4; ++i)
#pragma unroll
        for (int r = 0; r < TOPK; ++r) tk[i][r] = NEG_INIT;
    float psum[4] = {0.f, 0.f, 0.f, 0.f};
    int   pcnt[4] = {0, 0, 0, 0};

    __syncthreads();

    const int* rlabI = (const int*)(smem + LDS_RLAB);
    char* simw = smem + LDS_SIM + w * 2048;

#pragma unroll 1
    for (int tt = 0; tt < 2; ++tt) {
        const int mbase = w * 32 + tt * 16;                 // wave's 16 rows
        const float* Ab = rowm + (size_t)(bm * BLK_M + mbase + lc) * DIM + lq * 8;

        f32x4 acc[16];
#pragma unroll
        for (int f = 0; f < 16; ++f) acc[f] = (f32x4){0.f, 0.f, 0.f, 0.f};

        float4 fA[4], fB[4];                                // 4-deep prefetch
#pragma unroll
        for (int i = 0; i < 4; ++i) {
            fA[i] = *(const float4*)(Ab + i * 32);
            fB[i] = *(const float4*)(Ab + i * 32 + 4);
        }
#pragma unroll
        for (int ks = 0; ks < 16; ++ks) {
            const int sl = ks & 3;
            float4 a0 = fA[sl], a1 = fB[sl];
            if (ks < 12) {
                fA[sl] = *(const float4*)(Ab + (ks + 4) * 32);
                fB[sl] = *(const float4*)(Ab + (ks + 4) * 32 + 4);
            }
            a0.x *= 16.f; a0.y *= 16.f; a0.z *= 16.f; a0.w *= 16.f;
            a1.x *= 16.f; a1.y *= 16.f; a1.z *= 16.f; a1.w *= 16.f;
            long A = pack8(a0, a1);
            const char* bbase = smem + ks * 8192 + lq * 2048 + lc * 8;
#pragma unroll
            for (int f = 0; f < 16; ++f) {
                long B = *(const long*)(bbase + f * 128);
                acc[f] = __builtin_amdgcn_mfma_f32_16x16x32_fp8_fp8(A, B, acc[f], 0, 0, 0);
            }
        }

        // scan: 4 passes of 64 n each (lane owns nn = l -> n = h*64 + l)
#pragma unroll
        for (int h = 0; h < 4; ++h) {
#pragma unroll
            for (int ff = 0; ff < 4; ++ff) {
                int f = h * 4 + ff;
                u16x4 p;
                p[0] = f2bf(acc[f][0] * 0.00390625f);
                p[1] = f2bf(acc[f][1] * 0.00390625f);
                p[2] = f2bf(acc[f][2] * 0.00390625f);
                p[3] = f2bf(acc[f][3] * 0.00390625f);
                *(u16x4*)(simw + (ff * 16 + lc) * 32 + lq * 8) = p;
            }
            asm volatile("s_waitcnt lgkmcnt(0)" ::: "memory");
            u16x8 v0 = *(const u16x8*)(simw + l * 32);
            u16x8 v1 = *(const u16x8*)(simw + l * 32 + 16);
            float sv[16];
#pragma unroll
            for (int e = 0; e < 8; ++e) { sv[e] = bf2f(v0[e]); sv[8 + e] = bf2f(v1[e]); }
#pragma unroll
            for (int m = 0; m < 16; ++m) {
                float s = sv[m];
                int lab = rlabI[mbase + m];
                if (lab == clab_i[h]) {
                    if (s < 0.99999f) { psum[h] += 1.0f - s; pcnt[h] += 1; }
                } else if (s > tk[h][TOPK - 1]) {
                    float v = s;
#pragma unroll
                    for (int r = 0; r < TOPK; ++r) {
                        float old = tk[h][r]; bool gt = v > old;
                        tk[h][r] = gt ? v : old; v = gt ? old : v;
                    }
                }
            }
        }
    }

    __syncthreads();      // stream done; colm8 region reusable for merge lists
    float* mg = (float*)smem;
#pragma unroll
    for (int i = 0; i < 4; ++i) {
        float* dst = mg + (size_t)((i * 64 + l) * 8 + w) * 12;
#pragma unroll
        for (int r = 0; r < TOPK; ++r) dst[r] = tk[i][r];
        dst[10] = psum[i]; dst[11] = (float)pcnt[i];
    }
    __syncthreads();
    if (t < 256) {
        float L[8][TOPK]; float ps = 0.f, pc = 0.f;
#pragma unroll
        for (int u = 0; u < 8; ++u) {
            const float* src = mg + (size_t)(t * 8 + u) * 12;
#pragma unroll
            for (int r = 0; r < TOPK; ++r) L[u][r] = src[r];
            ps += src[10]; pc += src[11];
        }
        auto merge2 = [](float* o, const float* a, const float* b) {
            int ia = 0, ib = 0;
#pragma unroll
            for (int r = 0; r < TOPK; ++r) {
                float va = a[ia], vb = b[ib];
                bool ta = va >= vb;
                o[r] = ta ? va : vb;
                ia += ta; ib += !ta;
            }
        };
        float m01[TOPK], m23[TOPK], m45[TOPK], m67[TOPK], q0[TOPK], q1[TOPK], fin[TOPK];
        merge2(m01, L[0], L[1]); merge2(m23, L[2], L[3]);
        merge2(m45, L[4], L[5]); merge2(m67, L[6], L[7]);
        merge2(q0, m01, m23);    merge2(q1, m45, m67);
        merge2(fin, q0, q1);
        float* wp = part + ((size_t)t * NBM + bm) * PS;
#pragma unroll
        for (int r = 0; r < TOPK; ++r) wp[r] = fin[r];
        wp[10] = ps; wp[11] = pc;
    }
}

// K2: one block per col; merge 256 partial sorted top-10 lists + pos stats.
__global__ __launch_bounds__(256)
void k2_merge(const float* __restrict__ part, float* __restrict__ colloss) {
    __shared__ float vs[256 * TOPK];
    __shared__ float rv[256];
    __shared__ int   ri[256];
    const int c = blockIdx.x, t = threadIdx.x;
    const float* wp = part + ((size_t)c * NBM + t) * PS;
    float ps = wp[10], pc = wp[11];
#pragma unroll
    for (int r = 0; r < TOPK; ++r) vs[t * TOPK + r] = wp[r];

    rv[t] = ps; __syncthreads();
    for (int s = 128; s > 0; s >>= 1) { if (t < s) rv[t] += rv[t + s]; __syncthreads(); }
    float ps_tot = rv[0]; __syncthreads();
    rv[t] = pc; __syncthreads();
    for (int s = 128; s > 0; s >>= 1) { if (t < s) rv[t] += rv[t + s]; __syncthreads(); }
    float pc_tot = rv[0]; __syncthreads();

    int p = 0;
    float cand = vs[t * TOPK];
    float negsum = 0.f;
    for (int r = 0; r < TOPK; ++r) {
        rv[t] = cand; ri[t] = t; __syncthreads();
        for (int s = 128; s > 0; s >>= 1) {
            if (t < s && rv[t + s] > rv[t]) { rv[t] = rv[t + s]; ri[t] = ri[t + s]; }
            __syncthreads();
        }
        negsum += rv[0];
        if (t == ri[0]) { ++p; cand = (p < TOPK) ? vs[t * TOPK + p] : NEG_INIT; }
        __syncthreads();
    }

    if (t == 0) {
        float pos_loss = (pc_tot > 0.5f) ? 6.0f * ps_tot / pc_tot : 0.0f;
        colloss[c] = pos_loss + 15.0f * (negsum / (float)TOPK);
    }
}

// K3: final scalar reduce.
__global__ __launch_bounds__(256)
void k3_final(const float* __restrict__ colloss, float* __restrict__ out) {
    __shared__ float rv[256];
    const int t = threadIdx.x;
    rv[t] = colloss[t];
    __syncthreads();
    for (int s = 128; s > 0; s >>= 1) { if (t < s) rv[t] += rv[t + s]; __syncthreads(); }
    if (t == 0) out[0] = rv[0] / (float)N_COLS;
}

extern "C" void kernel_launch(void* const* d_in, const int* in_sizes, int n_in,
                              void* d_out, int out_size, void* d_ws, size_t ws_size,
                              hipStream_t stream) {
    const float* colm = (const float*)d_in[0];   // [256, 512] f32
    const int*   clab = (const int*)d_in[1];     // [256] i32
    const float* rowm = (const float*)d_in[2];   // [65536, 512] f32
    const int*   rlab = (const int*)d_in[3];     // [65536] i32

    float* part    = (float*)d_ws;                              // 256*256*12 f32 = 3 MB
    float* colloss = part + (size_t)N_COLS * NBM * PS;          // 256 f32
    unsigned char* colm8 = (unsigned char*)(colloss + 256);     // 128 KB fp8
    float* out = (float*)d_out;

    hipLaunchKernelGGL(k0_cvt, dim3(64), dim3(256), 0, stream, colm, colm8);
    hipLaunchKernelGGL(k1_mfma, dim3(NBLK), dim3(512), 0, stream,
                       colm8, clab, rowm, rlab, part);
    hipLaunchKernelGGL(k2_merge, dim3(N_COLS), dim3(256), 0, stream, part, colloss);
    hipLaunchKernelGGL(k3_final, dim3(1), dim3(256), 0, stream, colloss, out);
}

// Round 8
// 87.106 us; speedup vs baseline: 1.0650x; 1.0650x over previous
//
#include <hip/hip_runtime.h>
#include <stdint.h>

#define N_COLS 256
#define M_ROWS 65536
#define DIM    512
#define TOPK   10
#define PS     12
#define NBLK   256
#define BLK_M  256                 // m rows per k1 block
#define NBM    NBLK
#define NEG_INIT (-3.0e38f)
#define NEGF   (-1.0e4f)
#define SC     0.00390625f         // 1/256 (both operands scaled x16)

// k1 LDS map (bytes):
// [0, 131072)       colm8 [ks][kq][n][8]  (stream) | merge lists 80KB (tail)
// [131072, 147456)  sim: per-wave 2KB f16 [nloc 64][m 16]
// [147456, 148480)  possum[256] f32
// [148480, 149504)  poscnt[256] f32
// [149504, 149760)  clab u8[256]
#define L_SIM 131072
#define L_PS  147456
#define L_PC  148480
#define L_CL  149504
#define L_TOT 149760

typedef float  f32x4 __attribute__((ext_vector_type(4)));
typedef __fp16 f16x2 __attribute__((ext_vector_type(2)));

__device__ __forceinline__ void gload16(const void* g, void* l) {
    __builtin_amdgcn_global_load_lds(
        (const __attribute__((address_space(1))) void*)g,
        (__attribute__((address_space(3))) void*)l, 16, 0, 0);
}
__device__ __forceinline__ long pack8(float4 a, float4 b) {
    int lo = __builtin_amdgcn_cvt_pk_fp8_f32(a.x, a.y, 0, 0);
    lo = __builtin_amdgcn_cvt_pk_fp8_f32(a.z, a.w, lo, 1);
    int hi = __builtin_amdgcn_cvt_pk_fp8_f32(b.x, b.y, 0, 0);
    hi = __builtin_amdgcn_cvt_pk_fp8_f32(b.z, b.w, hi, 1);
    return (long)(((unsigned long)(unsigned)hi << 32) | (unsigned)lo);
}
__device__ __forceinline__ unsigned pkrtz_u(float a, float b) {
    return __builtin_bit_cast(unsigned, __builtin_amdgcn_cvt_pkrtz(a, b));
}
__device__ __forceinline__ f16x2 u2h(unsigned u) { return __builtin_bit_cast(f16x2, u); }
__device__ __forceinline__ unsigned pkmax(unsigned a, unsigned b) {
    unsigned r;
    asm("v_pk_max_f16 %0, %1, %2" : "=v"(r) : "v"(a), "v"(b));
    return r;
}
__device__ __forceinline__ float hmax16(uint4 a, uint4 b) {
    unsigned m = pkmax(pkmax(pkmax(a.x, a.y), pkmax(a.z, a.w)),
                       pkmax(pkmax(b.x, b.y), pkmax(b.z, b.w)));
    f16x2 h = u2h(m);
    return fmaxf((float)h[0], (float)h[1]);
}
__device__ __forceinline__ void ins10(float* tk, float v) {
#pragma unroll
    for (int r = 0; r < TOPK; ++r) {
        float old = tk[r]; bool gt = v > old;
        tk[r] = gt ? v : old; v = gt ? old : v;
    }
}

// K0: colm f32 -> fp8 (x16) in [ks][kq][n][8] layout; rlab -> u8 pack.
__global__ __launch_bounds__(256)
void k0_cvt(const float* __restrict__ colm, const int* __restrict__ rlab,
            unsigned char* __restrict__ colm8, unsigned char* __restrict__ rlab8) {
    int tid = blockIdx.x * 256 + threadIdx.x;            // 0..16383
    {
        int n = tid >> 6, ks = (tid >> 2) & 15, kq = tid & 3;
        const float* src = colm + n * DIM + ks * 32 + kq * 8;
        float4 a = *(const float4*)src, b = *(const float4*)(src + 4);
        a.x *= 16.f; a.y *= 16.f; a.z *= 16.f; a.w *= 16.f;
        b.x *= 16.f; b.y *= 16.f; b.z *= 16.f; b.w *= 16.f;
        *(long*)(colm8 + ks * 8192 + kq * 2048 + n * 8) = pack8(a, b);
    }
    {
        int4 r4 = *(const int4*)(rlab + tid * 4);
        unsigned p = (unsigned)(r4.x & 0xff) | ((unsigned)(r4.y & 0xff) << 8)
                   | ((unsigned)(r4.z & 0xff) << 16) | ((unsigned)(r4.w & 0xff) << 24);
        *(unsigned*)(rlab8 + tid * 4) = p;
    }
}

// stream 16 k-steps: rowm (16 rows/wave) global->reg->fp8 vs LDS-resident colm8.
__device__ __forceinline__ void stream16(const char* smem, const float* Ab,
                                         float4 (&fA)[4], float4 (&fB)[4],
                                         f32x4 (&acc)[16], int lq, int lc) {
#pragma unroll
    for (int f = 0; f < 16; ++f) acc[f] = (f32x4){0.f, 0.f, 0.f, 0.f};
#pragma unroll
    for (int ks = 0; ks < 16; ++ks) {
        const int sl = ks & 3;
        float4 a0 = fA[sl], a1 = fB[sl];
        if (ks < 12) {
            fA[sl] = *(const float4*)(Ab + (ks + 4) * 32);
            fB[sl] = *(const float4*)(Ab + (ks + 4) * 32 + 4);
        }
        a0.x *= 16.f; a0.y *= 16.f; a0.z *= 16.f; a0.w *= 16.f;
        a1.x *= 16.f; a1.y *= 16.f; a1.z *= 16.f; a1.w *= 16.f;
        long A = pack8(a0, a1);
        const char* bb = smem + ks * 8192 + lq * 2048 + lc * 8;
#pragma unroll
        for (int f = 0; f < 16; ++f) {
            long B = *(const long*)(bb + f * 128);
            acc[f] = __builtin_amdgcn_mfma_f32_16x16x32_fp8_fp8(A, B, acc[f], 0, 0, 0);
        }
    }
}

// per m-strip epilogue: mask+pos at write (lane owns one n per frag), f16 sim
// to wave-private LDS, then per-lane pure top-k scan with hmax16 pre-screen.
__device__ __forceinline__ void write_scan(const f32x4 (&acc)[16], unsigned rl4,
                                           const unsigned (&cl4)[4], float (&tk)[4][TOPK],
                                           char* simw, float* posS, float* cntS,
                                           int lq, int lc, int l) {
#pragma unroll
    for (int h = 0; h < 4; ++h) {
#pragma unroll
        for (int ff = 0; ff < 4; ++ff) {
            const int f = h * 4 + ff;
            float s0 = acc[f][0] * SC, s1 = acc[f][1] * SC,
                  s2 = acc[f][2] * SC, s3 = acc[f][3] * SC;
            unsigned cb = (cl4[h] >> (8 * ff)) & 0xffu;
            bool m0 = ((rl4 & 0xffu) == cb), m1 = (((rl4 >> 8) & 0xffu) == cb),
                 m2 = (((rl4 >> 16) & 0xffu) == cb), m3 = (((rl4 >> 24) & 0xffu) == cb);
            float p = (m0 && s0 < 0.99999f ? 1.f - s0 : 0.f)
                    + (m1 && s1 < 0.99999f ? 1.f - s1 : 0.f)
                    + (m2 && s2 < 0.99999f ? 1.f - s2 : 0.f)
                    + (m3 && s3 < 0.99999f ? 1.f - s3 : 0.f);
            float c = (m0 ? 1.f : 0.f) + (m1 ? 1.f : 0.f) + (m2 ? 1.f : 0.f) + (m3 ? 1.f : 0.f);
            if (m0 | m1 | m2 | m3) {
                atomicAdd(&posS[h * 64 + ff * 16 + lc], p);
                atomicAdd(&cntS[h * 64 + ff * 16 + lc], c);
            }
            float v0 = m0 ? NEGF : s0, v1 = m1 ? NEGF : s1,
                  v2 = m2 ? NEGF : s2, v3 = m3 ? NEGF : s3;
            uint2 pk;
            pk.x = pkrtz_u(v0, v1);
            pk.y = pkrtz_u(v2, v3);
            *(uint2*)(simw + (ff * 16 + lc) * 32 + lq * 8) = pk;
        }
        asm volatile("s_waitcnt lgkmcnt(0)" ::: "memory");
        uint4 r0 = *(const uint4*)(simw + l * 32);
        uint4 r1 = *(const uint4*)(simw + l * 32 + 16);
        if (hmax16(r0, r1) > tk[h][TOPK - 1]) {
            unsigned wds[8] = {r0.x, r0.y, r0.z, r0.w, r1.x, r1.y, r1.z, r1.w};
#pragma unroll
            for (int j = 0; j < 8; ++j) {
                f16x2 hv = u2h(wds[j]);
                float sa = (float)hv[0], sb = (float)hv[1];
                if (sa > tk[h][TOPK - 1]) ins10(tk[h], sa);
                if (sb > tk[h][TOPK - 1]) ins10(tk[h], sb);
            }
        }
    }
}

__global__ __launch_bounds__(512, 2)
void k1_mfma(const unsigned char* __restrict__ colm8g, const int* __restrict__ clab_g,
             const float* __restrict__ rowm, const unsigned char* __restrict__ rlab8g,
             float* __restrict__ part) {
    __shared__ __align__(16) char smem[L_TOT];
    const int t = threadIdx.x, bm = blockIdx.x;
    const int w = t >> 6, l = t & 63, lq = l >> 4, lc = l & 15;

#pragma unroll
    for (int i = 0; i < 16; ++i)
        gload16(colm8g + i * 8192 + w * 1024 + l * 16, (void*)(smem + i * 8192 + w * 1024));
    if (t < 64) {
        int4 c4 = *(const int4*)(clab_g + t * 4);
        unsigned p = (unsigned)(c4.x & 0xff) | ((unsigned)(c4.y & 0xff) << 8)
                   | ((unsigned)(c4.z & 0xff) << 16) | ((unsigned)(c4.w & 0xff) << 24);
        *(unsigned*)(smem + L_CL + t * 4) = p;
    }
    if (t < 256) { ((float*)(smem + L_PS))[t] = 0.f; ((float*)(smem + L_PC))[t] = 0.f; }
    __syncthreads();

    float tk[4][TOPK];
#pragma unroll
    for (int h = 0; h < 4; ++h)
#pragma unroll
        for (int r = 0; r < TOPK; ++r) tk[h][r] = NEG_INIT;

    unsigned cl4[4];
    {
        const unsigned char* cs = (const unsigned char*)(smem + L_CL);
#pragma unroll
        for (int h = 0; h < 4; ++h)
            cl4[h] = (unsigned)cs[h * 64 + lc] | ((unsigned)cs[h * 64 + 16 + lc] << 8)
                   | ((unsigned)cs[h * 64 + 32 + lc] << 16) | ((unsigned)cs[h * 64 + 48 + lc] << 24);
    }

    float* posS = (float*)(smem + L_PS);
    float* cntS = (float*)(smem + L_PC);
    char*  simw = smem + L_SIM + w * 2048;

    f32x4  acc[16];
    float4 fA[4], fB[4];

    const float* Ab0 = rowm + (size_t)(bm * BLK_M + w * 32 + lc) * DIM + lq * 8;
#pragma unroll
    for (int i = 0; i < 4; ++i) {
        fA[i] = *(const float4*)(Ab0 + i * 32);
        fB[i] = *(const float4*)(Ab0 + i * 32 + 4);
    }
    stream16(smem, Ab0, fA, fB, acc, lq, lc);

    unsigned rl4 = *(const unsigned*)(rlab8g + bm * BLK_M + w * 32 + lq * 4);
    const float* Ab1 = Ab0 + 16 * DIM;
#pragma unroll
    for (int i = 0; i < 4; ++i) {                   // prefetch strip 1 before scan
        fA[i] = *(const float4*)(Ab1 + i * 32);
        fB[i] = *(const float4*)(Ab1 + i * 32 + 4);
    }
    write_scan(acc, rl4, cl4, tk, simw, posS, cntS, lq, lc, l);

    stream16(smem, Ab1, fA, fB, acc, lq, lc);
    rl4 = *(const unsigned*)(rlab8g + bm * BLK_M + w * 32 + 16 + lq * 4);
    write_scan(acc, rl4, cl4, tk, simw, posS, cntS, lq, lc, l);

    // merge 8 wave-lists per n
    __syncthreads();
    float* mg = (float*)smem;                        // 256 n x 8 lists x 10 = 80 KB
#pragma unroll
    for (int h = 0; h < 4; ++h) {
        float* dst = mg + (size_t)((h * 64 + l) * 8 + w) * TOPK;
#pragma unroll
        for (int r = 0; r < TOPK; ++r) dst[r] = tk[h][r];
    }
    __syncthreads();
    if (t < 256) {
        float L[8][TOPK];
#pragma unroll
        for (int u = 0; u < 8; ++u) {
            const float* src = mg + (size_t)(t * 8 + u) * TOPK;
#pragma unroll
            for (int r = 0; r < TOPK; ++r) L[u][r] = src[r];
        }
        auto merge2 = [](float* o, const float* a, const float* b) {
            int ia = 0, ib = 0;
#pragma unroll
            for (int r = 0; r < TOPK; ++r) {
                float va = a[ia], vb = b[ib];
                bool ta = va >= vb;
                o[r] = ta ? va : vb;
                ia += ta; ib += !ta;
            }
        };
        float m01[TOPK], m23[TOPK], m45[TOPK], m67[TOPK], q0[TOPK], q1[TOPK], fin[TOPK];
        merge2(m01, L[0], L[1]); merge2(m23, L[2], L[3]);
        merge2(m45, L[4], L[5]); merge2(m67, L[6], L[7]);
        merge2(q0, m01, m23);    merge2(q1, m45, m67);
        merge2(fin, q0, q1);
        float* wp = part + ((size_t)t * NBM + bm) * PS;
#pragma unroll
        for (int r = 0; r < TOPK; ++r) wp[r] = fin[r];
        wp[10] = posS[t];
        wp[11] = cntS[t];
    }
}

// K2: one block per col; merge 256 partial sorted top-10 lists + pos stats.
__global__ __launch_bounds__(256)
void k2_merge(const float* __restrict__ part, float* __restrict__ colloss) {
    __shared__ float vs[256 * TOPK];
    __shared__ float rv[256];
    __shared__ int   ri[256];
    const int c = blockIdx.x, t = threadIdx.x;
    const float* wp = part + ((size_t)c * NBM + t) * PS;
    float ps = wp[10], pc = wp[11];
#pragma unroll
    for (int r = 0; r < TOPK; ++r) vs[t * TOPK + r] = wp[r];

    rv[t] = ps; __syncthreads();
    for (int s = 128; s > 0; s >>= 1) { if (t < s) rv[t] += rv[t + s]; __syncthreads(); }
    float ps_tot = rv[0]; __syncthreads();
    rv[t] = pc; __syncthreads();
    for (int s = 128; s > 0; s >>= 1) { if (t < s) rv[t] += rv[t + s]; __syncthreads(); }
    float pc_tot = rv[0]; __syncthreads();

    int p = 0;
    float cand = vs[t * TOPK];
    float negsum = 0.f;
    for (int r = 0; r < TOPK; ++r) {
        rv[t] = cand; ri[t] = t; __syncthreads();
        for (int s = 128; s > 0; s >>= 1) {
            if (t < s && rv[t + s] > rv[t]) { rv[t] = rv[t + s]; ri[t] = ri[t + s]; }
            __syncthreads();
        }
        negsum += rv[0];
        if (t == ri[0]) { ++p; cand = (p < TOPK) ? vs[t * TOPK + p] : NEG_INIT; }
        __syncthreads();
    }

    if (t == 0) {
        float pos_loss = (pc_tot > 0.5f) ? 6.0f * ps_tot / pc_tot : 0.0f;
        colloss[c] = pos_loss + 15.0f * (negsum / (float)TOPK);
    }
}

// K3: final scalar reduce.
__global__ __launch_bounds__(256)
void k3_final(const float* __restrict__ colloss, float* __restrict__ out) {
    __shared__ float rv[256];
    const int t = threadIdx.x;
    rv[t] = colloss[t];
    __syncthreads();
    for (int s = 128; s > 0; s >>= 1) { if (t < s) rv[t] += rv[t + s]; __syncthreads(); }
    if (t == 0) out[0] = rv[0] / (float)N_COLS;
}

extern "C" void kernel_launch(void* const* d_in, const int* in_sizes, int n_in,
                              void* d_out, int out_size, void* d_ws, size_t ws_size,
                              hipStream_t stream) {
    const float* colm = (const float*)d_in[0];   // [256, 512] f32
    const int*   clab = (const int*)d_in[1];     // [256] i32
    const float* rowm = (const float*)d_in[2];   // [65536, 512] f32
    const int*   rlab = (const int*)d_in[3];     // [65536] i32

    float* part    = (float*)d_ws;                              // 256*256*12 f32 = 3.1 MB
    float* colloss = part + (size_t)N_COLS * NBM * PS;          // 256 f32
    unsigned char* colm8 = (unsigned char*)(colloss + 256);     // 128 KB
    unsigned char* rlab8 = colm8 + 131072;                      // 64 KB
    float* out = (float*)d_out;

    hipLaunchKernelGGL(k0_cvt, dim3(64), dim3(256), 0, stream, colm, rlab, colm8, rlab8);
    hipLaunchKernelGGL(k1_mfma, dim3(NBLK), dim3(512), 0, stream,
                       colm8, clab, rowm, rlab8, part);
    hipLaunchKernelGGL(k2_merge, dim3(N_COLS), dim3(256), 0, stream, part, colloss);
    hipLaunchKernelGGL(k3_final, dim3(1), dim3(256), 0, stream, colloss, out);
}